// Round 12
// baseline (310.405 us; speedup 1.0000x reference)
//
#include <hip/hip_runtime.h>

#define SEQ 512
#define BATCH 8192
#define LOG2E  1.44269504088896340736f
#define LOG2E2 2.88539008177792681472f   // 2*log2(e)

typedef _Float16 f16x8 __attribute__((ext_vector_type(8)));
typedef float    f32x4 __attribute__((ext_vector_type(4)));
typedef unsigned u32x4 __attribute__((ext_vector_type(4)));

__device__ __forceinline__ float fexp2(float x) { return __builtin_amdgcn_exp2f(x); }
__device__ __forceinline__ float frcp(float x)  { return __builtin_amdgcn_rcpf(x); }
__device__ __forceinline__ unsigned pkf16(_Float16 a, _Float16 b) {
    return (unsigned)__builtin_bit_cast(unsigned short, a) |
           ((unsigned)__builtin_bit_cast(unsigned short, b) << 16);
}

// MFMA LSTM, all-register recurrence, CHAIN-MINIMIZED (r9 + surgery).
// One wave per 16 batch elements. Pipelined step t computes L0[t+1], L1[t];
// both read v = [x[t+1]; h1[t]; h2[t-1]] -> z(80) = W(80x22-perm)·v via
// 5 row-tiles of mfma_f32_16x16x32_f16.
// Split precision (r8/r9-verified, absmax 6.1e-5):
//   z = W_hi·v_hi + W_lo·v_hi + W_hi·v_lo + bias
// CHAIN CHANGES vs r9:
//  - the 3 MFMAs per tile are INDEPENDENT (bias in P_hi's C, zeros in the
//    others) + a 2-deep f32x4 add tree  [was: 3 serially-dependent MFMAs]
//  - tanh(c) stage: 5 independent exp2->rcp->fma chains [was cross-tile
//    paired rcps adding muls to the chain]
//  - B assembled as packed dwords (cvt/sub/pack trees) [was elem inserts]
// Layout (r9, verified): pair P=4T+q at v-row k=8q+(2+T); D gives lane (q,e)
// pairs {4T+q}, 4 gates in 4 acc regs -> producer lane == consumer lane,
// recurrence entirely in registers. x in k=0,1 (q=0); A zeros unused slots.
__global__ __launch_bounds__(64) void lstm2_fc_mfma(
    const float* __restrict__ x,
    const float* __restrict__ w_ih0, const float* __restrict__ w_hh0,
    const float* __restrict__ b_ih0, const float* __restrict__ b_hh0,
    const float* __restrict__ w_ih1, const float* __restrict__ w_hh1,
    const float* __restrict__ b_ih1, const float* __restrict__ b_hh1,
    const float* __restrict__ fc_w, const float* __restrict__ fc_b,
    float* __restrict__ out)
{
    __shared__ float hfc[16][10];

    const int lane = threadIdx.x;
    const int e    = lane & 15;      // elem column / A-row-in-tile
    const int q    = lane >> 4;      // K-chunk for A/B; row-quad for C/D
    const int Eb   = blockIdx.x * 16;
    const bool qz  = (q == 0);

    // ---- A fragments hi/lo (prescaled) + C bias ----
    f16x8 ahi[5], alo[5];
    f32x4 cb[5];
    bool  l1p[5];
    #pragma unroll
    for (int T = 0; T < 5; ++T) {
        const int Pa = 4 * T + (e >> 2), Ga = e & 3;   // A row e -> pair/gate
        const int La = (Pa >= 10);
        const int Ua = Pa - La * 10;
        const int wr = Ga * 10 + Ua;                   // torch row in 40-block
        const float m = (Ga == 2) ? LOG2E2 : -LOG2E;
        #pragma unroll
        for (int j = 0; j < 8; ++j) {
            const int k = q * 8 + j;
            float w = 0.0f;
            if (k < 2) {                               // x slots (q==0, j<2)
                w = La ? 0.0f : w_ih0[wr * 2 + k];
            } else if (j >= 2 && j <= 6) {             // pair p = 4*(j-2)+q
                const int p = 4 * (j - 2) + q;
                if (p < 10) w = La ? w_ih1[wr * 10 + p] : w_hh0[wr * 10 + p];
                else        w = La ? w_hh1[wr * 10 + (p - 10)] : 0.0f;
            }
            const float wm = m * w;
            const _Float16 wh = (_Float16)wm;
            ahi[T][j] = wh;
            alo[T][j] = (_Float16)(wm - (float)wh);
        }
        const int Pc = 4 * T + q;                      // C/D pair for this lane
        l1p[T] = (Pc >= 10);
        const int Lc = (Pc >= 10);
        const int Uc = Pc - Lc * 10;
        #pragma unroll
        for (int r = 0; r < 4; ++r) {
            const int wrc = r * 10 + Uc;
            const float mc = (r == 2) ? LOG2E2 : -LOG2E;
            cb[T][r] = mc * (Lc ? (b_ih1[wrc] + b_hh1[wrc])
                                : (b_ih0[wrc] + b_hh0[wrc]));
        }
    }

    // ---- B state as packed dwords (j0,1|j2,3|j4,5|j6,7 per dword) ----
    unsigned bd0 = 0u, bd1 = 0u, bd2 = 0u, bd3 = 0u;   // v_hi
    unsigned bl0 = 0u, bl1 = 0u, bl2 = 0u, bl3 = 0u;   // v_lo

    // ---- x prefetch: x[0], x[1], then 8-step register chunks ----
    const float* xe = x + ((size_t)Eb + e) * 2;
    const float2 x0 = *(const float2*)xe;
    const float2 x1 = *(const float2*)(xe + (size_t)1 * BATCH * 2);
    float2 xr0[8], xr1[8];
    #pragma unroll
    for (int i = 0; i < 8; ++i) xr0[i] = *(const float2*)(xe + (size_t)(2 + i) * BATCH * 2);
    #pragma unroll
    for (int i = 0; i < 8; ++i) xr1[i] = *(const float2*)(xe + (size_t)(10 + i) * BATCH * 2);

    // insert x[0] (q==0 lanes; others keep 0)
    {
        const _Float16 xa = (_Float16)x0.x, xb = (_Float16)x0.y;
        bd0 = qz ? pkf16(xa, xb) : 0u;
        bl0 = qz ? pkf16((_Float16)(x0.x - (float)xa),
                         (_Float16)(x0.y - (float)xb)) : 0u;
    }

    float cst[5] = {0.f, 0.f, 0.f, 0.f, 0.f};
    float hT[5];
    const f32x4 kZ = {0.f, 0.f, 0.f, 0.f};

    // gate stage for tile T (shared 4-gate rcp; c update; sO saved)
#define ACT(T, ZZ, SUP)                                                        \
    {                                                                          \
        const float a0 = 1.0f + fexp2(ZZ[0]);                                  \
        const float a1 = 1.0f + fexp2(ZZ[1]);                                  \
        const float a2 = 1.0f + fexp2(ZZ[2]);                                  \
        const float a3 = 1.0f + fexp2(ZZ[3]);                                  \
        const float m1 = a0 * a1, m2 = a2 * a3;                                \
        const float pq_ = frcp(m1 * m2);                                       \
        const float pif = m2 * pq_, pgo = m1 * pq_;                            \
        const float si = a1 * pif, sf = a0 * pif;                              \
        const float tg = fmaf(-2.0f, a3 * pgo, 1.0f);                          \
        sO[T] = a2 * pgo;                                                      \
        float cn = fmaf(sf, cst[T], si * tg);                                  \
        if (SUP) cn = l1p[T] ? 0.0f : cn;  /* prologue: L1 pairs stay 0 */     \
        cst[T] = cn;                                                           \
    }

    // one pipelined step: consume B (bd*/bl*), update in place; XIN = next x.
#define STEP(XIN, SUP)                                                         \
    {                                                                          \
        const f16x8 Bh = __builtin_bit_cast(f16x8, (u32x4){bd0, bd1, bd2, bd3}); \
        const f16x8 Bl = __builtin_bit_cast(f16x8, (u32x4){bl0, bl1, bl2, bl3}); \
        /* 15 INDEPENDENT MFMAs (no serial accumulate), then add tree */       \
        const f32x4 pA0 = __builtin_amdgcn_mfma_f32_16x16x32_f16(ahi[0], Bh, cb[0], 0, 0, 0); \
        const f32x4 pA1 = __builtin_amdgcn_mfma_f32_16x16x32_f16(ahi[1], Bh, cb[1], 0, 0, 0); \
        const f32x4 pA2 = __builtin_amdgcn_mfma_f32_16x16x32_f16(ahi[2], Bh, cb[2], 0, 0, 0); \
        const f32x4 pA3 = __builtin_amdgcn_mfma_f32_16x16x32_f16(ahi[3], Bh, cb[3], 0, 0, 0); \
        const f32x4 pA4 = __builtin_amdgcn_mfma_f32_16x16x32_f16(ahi[4], Bh, cb[4], 0, 0, 0); \
        const f32x4 pB0 = __builtin_amdgcn_mfma_f32_16x16x32_f16(alo[0], Bh, kZ, 0, 0, 0); \
        const f32x4 pB1 = __builtin_amdgcn_mfma_f32_16x16x32_f16(alo[1], Bh, kZ, 0, 0, 0); \
        const f32x4 pB2 = __builtin_amdgcn_mfma_f32_16x16x32_f16(alo[2], Bh, kZ, 0, 0, 0); \
        const f32x4 pB3 = __builtin_amdgcn_mfma_f32_16x16x32_f16(alo[3], Bh, kZ, 0, 0, 0); \
        const f32x4 pB4 = __builtin_amdgcn_mfma_f32_16x16x32_f16(alo[4], Bh, kZ, 0, 0, 0); \
        const f32x4 pC0 = __builtin_amdgcn_mfma_f32_16x16x32_f16(ahi[0], Bl, kZ, 0, 0, 0); \
        const f32x4 pC1 = __builtin_amdgcn_mfma_f32_16x16x32_f16(ahi[1], Bl, kZ, 0, 0, 0); \
        const f32x4 pC2 = __builtin_amdgcn_mfma_f32_16x16x32_f16(ahi[2], Bl, kZ, 0, 0, 0); \
        const f32x4 pC3 = __builtin_amdgcn_mfma_f32_16x16x32_f16(ahi[3], Bl, kZ, 0, 0, 0); \
        const f32x4 pC4 = __builtin_amdgcn_mfma_f32_16x16x32_f16(ahi[4], Bl, kZ, 0, 0, 0); \
        const f32x4 z0 = (pA0 + pB0) + pC0;                                    \
        const f32x4 z1 = (pA1 + pB1) + pC1;                                    \
        const f32x4 z2 = (pA2 + pB2) + pC2;                                    \
        const f32x4 z3 = (pA3 + pB3) + pC3;                                    \
        const f32x4 z4 = (pA4 + pB4) + pC4;                                    \
        float sO[5];                                                           \
        ACT(0, z0, SUP) ACT(1, z1, SUP) ACT(2, z2, SUP)                        \
        ACT(3, z3, SUP) ACT(4, z4, SUP)                                        \
        /* 5 independent tanh(c) chains */                                     \
        _Pragma("unroll")                                                      \
        for (int T = 0; T < 5; ++T) {                                          \
            const float eT = 1.0f + fexp2(LOG2E2 * cst[T]);                    \
            hT[T] = sO[T] * fmaf(-2.0f, frcp(eT), 1.0f);                       \
        }                                                                      \
        /* repack B: hi dwords + lo dwords (trees, depth ~4) */                \
        const _Float16 h0 = (_Float16)hT[0], h1v = (_Float16)hT[1];            \
        const _Float16 h2v = (_Float16)hT[2], h3v = (_Float16)hT[3];           \
        const _Float16 h4v = (_Float16)hT[4];                                  \
        bd1 = pkf16(h0, h1v);                                                  \
        bd2 = pkf16(h2v, h3v);                                                 \
        bd3 = pkf16(h4v, (_Float16)0.f);                                       \
        bl1 = pkf16((_Float16)(hT[0] - (float)h0),                             \
                    (_Float16)(hT[1] - (float)h1v));                           \
        bl2 = pkf16((_Float16)(hT[2] - (float)h2v),                            \
                    (_Float16)(hT[3] - (float)h3v));                           \
        bl3 = pkf16((_Float16)(hT[4] - (float)h4v), (_Float16)0.f);            \
        const _Float16 xa = (_Float16)(XIN).x, xb = (_Float16)(XIN).y;         \
        bd0 = qz ? pkf16(xa, xb) : 0u;                                         \
        bl0 = qz ? pkf16((_Float16)((XIN).x - (float)xa),                      \
                         (_Float16)((XIN).y - (float)xb)) : 0u;                \
    }

    // prologue (t=-1): v=[x0,0,0] -> h1[0]; L1 pairs suppressed; insert x[1]
    STEP(x1, 1)

    // main: 32 iters x 16 steps = 512 (t = 0..511); step t inserts x[t+2]
    for (int cc = 0; cc < 32; ++cc) {
        #pragma unroll
        for (int s = 0; s < 8; ++s) STEP(xr0[s], 0)        // t=16cc+s
        #pragma unroll
        for (int i = 0; i < 8; ++i) {                      // reload chunk
            int ti = 16 * cc + 18 + i; if (ti > 511) ti = 511;
            xr0[i] = *(const float2*)(xe + (size_t)ti * BATCH * 2);
        }
        #pragma unroll
        for (int s = 0; s < 8; ++s) STEP(xr1[s], 0)        // t=16cc+8+s
        #pragma unroll
        for (int i = 0; i < 8; ++i) {
            int ti = 16 * cc + 26 + i; if (ti > 511) ti = 511;
            xr1[i] = *(const float2*)(xe + (size_t)ti * BATCH * 2);
        }
    }
#undef STEP
#undef ACT

    // ---- FC: L1 pairs of step 511 hold h2[511] ----
    if (q >= 2) hfc[e][q - 2] = hT[2];            // pairs 10,11 -> units 0,1
    hfc[e][2 + q] = hT[3];                        // pairs 12..15 -> units 2..5
    hfc[e][6 + q] = hT[4];                        // pairs 16..19 -> units 6..9
    __syncthreads();
    if (lane < 32) {
        const int ee = lane >> 1, jj = lane & 1;
        float acc = fc_b[jj];
        #pragma unroll
        for (int u = 0; u < 10; ++u)
            acc = fmaf(fc_w[jj * 10 + u], hfc[ee][u], acc);
        out[((size_t)Eb + ee) * 2 + jj] = acc;
    }
}

extern "C" void kernel_launch(void* const* d_in, const int* in_sizes, int n_in,
                              void* d_out, int out_size, void* d_ws, size_t ws_size,
                              hipStream_t stream) {
    const float* x     = (const float*)d_in[0];
    const float* w_ih0 = (const float*)d_in[1];
    const float* w_hh0 = (const float*)d_in[2];
    const float* b_ih0 = (const float*)d_in[3];
    const float* b_hh0 = (const float*)d_in[4];
    const float* w_ih1 = (const float*)d_in[5];
    const float* w_hh1 = (const float*)d_in[6];
    const float* b_ih1 = (const float*)d_in[7];
    const float* b_hh1 = (const float*)d_in[8];
    const float* fc_w  = (const float*)d_in[9];
    const float* fc_b  = (const float*)d_in[10];
    float* out = (float*)d_out;

    const int threads = 64;                   // 1 wave = 16 batch elements
    const int blocks  = BATCH / 16;           // 512 waves
    lstm2_fc_mfma<<<blocks, threads, 0, stream>>>(
        x, w_ih0, w_hh0, b_ih0, b_hh0,
        w_ih1, w_hh1, b_ih1, b_hh1, fc_w, fc_b, out);
}

// Round 13
// 276.096 us; speedup vs baseline: 1.1243x; 1.1243x over previous
//
#include <hip/hip_runtime.h>

#define SEQ 512
#define BATCH 8192
#define LOG2E  1.44269504088896340736f
#define LOG2E2 2.88539008177792681472f   // 2*log2(e)

typedef _Float16 f16x8 __attribute__((ext_vector_type(8)));
typedef float    f32x4 __attribute__((ext_vector_type(4)));
typedef unsigned u32x4 __attribute__((ext_vector_type(4)));

__device__ __forceinline__ float fexp2(float x) { return __builtin_amdgcn_exp2f(x); }
__device__ __forceinline__ float frcp(float x)  { return __builtin_amdgcn_rcpf(x); }
__device__ __forceinline__ unsigned pkf16(_Float16 a, _Float16 b) {
    return (unsigned)__builtin_bit_cast(unsigned short, a) |
           ((unsigned)__builtin_bit_cast(unsigned short, b) << 16);
}

// MFMA LSTM, all-register recurrence, ISSUE-MINIMIZED (r9 skeleton).
// One wave per 16 batch elements; pipelined step t computes L0[t+1], L1[t],
// both reading v = [x[t+1]; h1[t]; h2[t-1]] -> z(80) = W·v, 5 row-tiles of
// mfma_f32_16x16x32_f16, depth-2 accumulate:
//   z = W_hi·v + W_lo·v + bias      (W split; v carried hi-f16 only)
// h is hi-f16 only (r11 measured this path: absmax 4.9e-4 < 1.62e-3 thr).
// x is EXACT: x_hi in k=0,1 (q0 j0,j1); x_lo in k=7 (q0 j7) and k=15
// (q1 j7) with duplicated w_ih0 columns in A — no extra MFMA.
// Layout (r9-verified): pair P=4T+q at k=8q+(2+T); D gives lane (q,e) pairs
// {4T+q} (4 gates in 4 acc regs) -> producer lane == consumer lane; the
// recurrence never leaves registers.
// x per-step B-dword (bd0) and x_lo half (ut) are PRE-PACKED during the
// 8-step bulk prefetch — off the critical path, out of the step's issue.
__global__ __launch_bounds__(64) void lstm2_fc_mfma(
    const float* __restrict__ x,
    const float* __restrict__ w_ih0, const float* __restrict__ w_hh0,
    const float* __restrict__ b_ih0, const float* __restrict__ b_hh0,
    const float* __restrict__ w_ih1, const float* __restrict__ w_hh1,
    const float* __restrict__ b_ih1, const float* __restrict__ b_hh1,
    const float* __restrict__ fc_w, const float* __restrict__ fc_b,
    float* __restrict__ out)
{
    __shared__ float hfc[16][10];

    const int lane = threadIdx.x;
    const int e    = lane & 15;      // elem column / A-row-in-tile
    const int q    = lane >> 4;      // K-chunk for A/B; row-quad for C/D
    const int Eb   = blockIdx.x * 16;
    const bool qz  = (q == 0);

    // ---- A fragments hi/lo (prescaled) + C bias ----
    f16x8 ahi[5], alo[5];
    f32x4 cb[5];
    bool  l1p[5];
    #pragma unroll
    for (int T = 0; T < 5; ++T) {
        const int Pa = 4 * T + (e >> 2), Ga = e & 3;   // A row e -> pair/gate
        const int La = (Pa >= 10);
        const int Ua = Pa - La * 10;
        const int wr = Ga * 10 + Ua;                   // torch row in 40-block
        const float m = (Ga == 2) ? LOG2E2 : -LOG2E;
        #pragma unroll
        for (int j = 0; j < 8; ++j) {
            const int k = q * 8 + j;
            float w = 0.0f;
            if (k < 2) {                               // x_hi slots (q0, j<2)
                w = La ? 0.0f : w_ih0[wr * 2 + k];
            } else if (j >= 2 && j <= 6) {             // h pair p = 4*(j-2)+q
                const int p = 4 * (j - 2) + q;
                if (p < 10) w = La ? w_ih1[wr * 10 + p] : w_hh0[wr * 10 + p];
                else        w = La ? w_hh1[wr * 10 + (p - 10)] : 0.0f;
            } else if (j == 7) {                       // x_lo dup columns
                if (q == 0)      w = La ? 0.0f : w_ih0[wr * 2 + 0];
                else if (q == 1) w = La ? 0.0f : w_ih0[wr * 2 + 1];
            }
            const float wm = m * w;
            const _Float16 wh = (_Float16)wm;
            ahi[T][j] = wh;
            alo[T][j] = (_Float16)(wm - (float)wh);
        }
        const int Pc = 4 * T + q;                      // C/D pair for this lane
        l1p[T] = (Pc >= 10);
        const int Lc = (Pc >= 10);
        const int Uc = Pc - Lc * 10;
        #pragma unroll
        for (int r = 0; r < 4; ++r) {
            const int wrc = r * 10 + Uc;
            const float mc = (r == 2) ? LOG2E2 : -LOG2E;
            cb[T][r] = mc * (Lc ? (b_ih1[wrc] + b_hh1[wrc])
                                : (b_ih0[wrc] + b_hh0[wrc]));
        }
    }

    // ---- x prefetch + pre-pack (off the step's critical path) ----
    const float* xe = x + ((size_t)Eb + e) * 2;
    // PKX: float2 -> (bd0 dword, x_lo f16 half), lane-selected
#define PKX(V, UX, UT)                                                         \
    {                                                                          \
        const _Float16 ha = (_Float16)(V).x, hb = (_Float16)(V).y;             \
        (UX) = qz ? pkf16(ha, hb) : 0u;                                        \
        const _Float16 la = (_Float16)((V).x - (float)ha);                     \
        const _Float16 lb = (_Float16)((V).y - (float)hb);                     \
        (UT) = qz ? la : ((q == 1) ? lb : (_Float16)0.f);                      \
    }

    unsigned ux0s, ux1s; _Float16 ut0s, ut1s;
    {
        const float2 v0 = *(const float2*)xe;
        const float2 v1 = *(const float2*)(xe + (size_t)1 * BATCH * 2);
        PKX(v0, ux0s, ut0s)
        PKX(v1, ux1s, ut1s)
    }
    unsigned uxA[8], uxB[8]; _Float16 utA[8], utB[8];
    #pragma unroll
    for (int i = 0; i < 8; ++i) {
        const float2 v = *(const float2*)(xe + (size_t)(2 + i) * BATCH * 2);
        PKX(v, uxA[i], utA[i])
    }
    #pragma unroll
    for (int i = 0; i < 8; ++i) {
        const float2 v = *(const float2*)(xe + (size_t)(10 + i) * BATCH * 2);
        PKX(v, uxB[i], utB[i])
    }

    // ---- B state (hi dwords only) ----
    unsigned bd0 = ux0s, bd1 = 0u, bd2 = 0u,
             bd3 = pkf16((_Float16)0.f, ut0s);

    float cst[5] = {0.f, 0.f, 0.f, 0.f, 0.f};
    float hT[5];

    // gate stage for tile T: 4 gates, one shared rcp, c update
#define ACT(T, ZZ, SUP)                                                        \
    {                                                                          \
        const float a0 = 1.0f + fexp2(ZZ[0]);                                  \
        const float a1 = 1.0f + fexp2(ZZ[1]);                                  \
        const float a2 = 1.0f + fexp2(ZZ[2]);                                  \
        const float a3 = 1.0f + fexp2(ZZ[3]);                                  \
        const float m1 = a0 * a1, m2 = a2 * a3;                                \
        const float pq_ = frcp(m1 * m2);                                       \
        const float pif = m2 * pq_, pgo = m1 * pq_;                            \
        const float si = a1 * pif, sf = a0 * pif;                              \
        const float tg = fmaf(-2.0f, a3 * pgo, 1.0f);                          \
        sO[T] = a2 * pgo;                                                      \
        float cn = fmaf(sf, cst[T], si * tg);                                  \
        if (SUP) cn = l1p[T] ? 0.0f : cn;  /* prologue: L1 pairs stay 0 */     \
        cst[T] = cn;                                                           \
        eC[T] = 1.0f + fexp2(LOG2E2 * cn);                                     \
    }

    // one step: consume B, update B in place; (UX,UT) = pre-packed next x
#define STEP(UX, UT, SUP)                                                      \
    {                                                                          \
        const f16x8 Bh = __builtin_bit_cast(f16x8, (u32x4){bd0, bd1, bd2, bd3}); \
        f32x4 z0 = __builtin_amdgcn_mfma_f32_16x16x32_f16(ahi[0], Bh, cb[0], 0, 0, 0); \
        f32x4 z1 = __builtin_amdgcn_mfma_f32_16x16x32_f16(ahi[1], Bh, cb[1], 0, 0, 0); \
        f32x4 z2 = __builtin_amdgcn_mfma_f32_16x16x32_f16(ahi[2], Bh, cb[2], 0, 0, 0); \
        f32x4 z3 = __builtin_amdgcn_mfma_f32_16x16x32_f16(ahi[3], Bh, cb[3], 0, 0, 0); \
        f32x4 z4 = __builtin_amdgcn_mfma_f32_16x16x32_f16(ahi[4], Bh, cb[4], 0, 0, 0); \
        z0 = __builtin_amdgcn_mfma_f32_16x16x32_f16(alo[0], Bh, z0, 0, 0, 0);  \
        z1 = __builtin_amdgcn_mfma_f32_16x16x32_f16(alo[1], Bh, z1, 0, 0, 0);  \
        z2 = __builtin_amdgcn_mfma_f32_16x16x32_f16(alo[2], Bh, z2, 0, 0, 0);  \
        z3 = __builtin_amdgcn_mfma_f32_16x16x32_f16(alo[3], Bh, z3, 0, 0, 0);  \
        z4 = __builtin_amdgcn_mfma_f32_16x16x32_f16(alo[4], Bh, z4, 0, 0, 0);  \
        float eC[5], sO[5];                                                    \
        ACT(0, z0, SUP) ACT(1, z1, SUP) ACT(2, z2, SUP)                        \
        ACT(3, z3, SUP) ACT(4, z4, SUP)                                        \
        const float p01 = frcp(eC[0] * eC[1]);                                 \
        const float p23 = frcp(eC[2] * eC[3]);                                 \
        const float p4  = frcp(eC[4]);                                         \
        hT[0] = sO[0] * fmaf(-2.0f, eC[1] * p01, 1.0f);                        \
        hT[1] = sO[1] * fmaf(-2.0f, eC[0] * p01, 1.0f);                        \
        hT[2] = sO[2] * fmaf(-2.0f, eC[3] * p23, 1.0f);                        \
        hT[3] = sO[3] * fmaf(-2.0f, eC[2] * p23, 1.0f);                        \
        hT[4] = sO[4] * fmaf(-2.0f, p4, 1.0f);                                 \
        bd1 = pkf16((_Float16)hT[0], (_Float16)hT[1]);                         \
        bd2 = pkf16((_Float16)hT[2], (_Float16)hT[3]);                         \
        bd3 = pkf16((_Float16)hT[4], (UT));                                    \
        bd0 = (UX);                                                            \
    }

    // prologue (t=-1): v=[x0,0,0] -> h1[0]; L1 pairs suppressed; insert x[1]
    STEP(ux1s, ut1s, 1)

    // main: 32 iters x 16 steps = 512; step n inserts x[n+1]
    for (int cc = 0; cc < 32; ++cc) {
        #pragma unroll
        for (int s = 0; s < 8; ++s) STEP(uxA[s], utA[s], 0)
        #pragma unroll
        for (int i = 0; i < 8; ++i) {
            int ti = 16 * cc + 18 + i; if (ti > 511) ti = 511;
            const float2 v = *(const float2*)(xe + (size_t)ti * BATCH * 2);
            PKX(v, uxA[i], utA[i])
        }
        #pragma unroll
        for (int s = 0; s < 8; ++s) STEP(uxB[s], utB[s], 0)
        #pragma unroll
        for (int i = 0; i < 8; ++i) {
            int ti = 16 * cc + 26 + i; if (ti > 511) ti = 511;
            const float2 v = *(const float2*)(xe + (size_t)ti * BATCH * 2);
            PKX(v, uxB[i], utB[i])
        }
    }
#undef STEP
#undef ACT
#undef PKX

    // ---- FC: L1 pairs of the last step hold h2[511] ----
    if (q >= 2) hfc[e][q - 2] = hT[2];            // pairs 10,11 -> units 0,1
    hfc[e][2 + q] = hT[3];                        // pairs 12..15 -> units 2..5
    hfc[e][6 + q] = hT[4];                        // pairs 16..19 -> units 6..9
    __syncthreads();
    if (lane < 32) {
        const int ee = lane >> 1, jj = lane & 1;
        float acc = fc_b[jj];
        #pragma unroll
        for (int u = 0; u < 10; ++u)
            acc = fmaf(fc_w[jj * 10 + u], hfc[ee][u], acc);
        out[((size_t)Eb + ee) * 2 + jj] = acc;
    }
}

extern "C" void kernel_launch(void* const* d_in, const int* in_sizes, int n_in,
                              void* d_out, int out_size, void* d_ws, size_t ws_size,
                              hipStream_t stream) {
    const float* x     = (const float*)d_in[0];
    const float* w_ih0 = (const float*)d_in[1];
    const float* w_hh0 = (const float*)d_in[2];
    const float* b_ih0 = (const float*)d_in[3];
    const float* b_hh0 = (const float*)d_in[4];
    const float* w_ih1 = (const float*)d_in[5];
    const float* w_hh1 = (const float*)d_in[6];
    const float* b_ih1 = (const float*)d_in[7];
    const float* b_hh1 = (const float*)d_in[8];
    const float* fc_w  = (const float*)d_in[9];
    const float* fc_b  = (const float*)d_in[10];
    float* out = (float*)d_out;

    const int threads = 64;                   // 1 wave = 16 batch elements
    const int blocks  = BATCH / 16;           // 512 waves
    lstm2_fc_mfma<<<blocks, threads, 0, stream>>>(
        x, w_ih0, w_hh0, b_ih0, b_hh0,
        w_ih1, w_hh1, b_ih1, b_hh1, fc_w, fc_b, out);
}